// Round 11
// baseline (10257.047 us; speedup 1.0000x reference)
//
#include <hip/hip_runtime.h>

typedef _Float16 half_t;
typedef _Float16 half8 __attribute__((ext_vector_type(8)));
typedef _Float16 half4v __attribute__((ext_vector_type(4)));
typedef float f32x4 __attribute__((ext_vector_type(4)));

#define DI __device__ __forceinline__

constexpr int Bsz = 256;   // batch
constexpr int Tsz = 128;   // seq len
constexpr int Fsz = 32;    // feature
constexpr int Hsz = 1024;  // hidden
constexpr int NG  = 4096;  // 4*H gate rows
constexpr int K1  = 1152;  // L0 GEMM K: [h(1024) | x(32) | pad(96)=0]
constexpr int K2  = 2048;  // L1 GEMM K: [h0 | h1]
constexpr int RSTR = 84;   // LDS reduce stride
constexpr int CSTR = 24;   // LDS c-state stride (96B rows: 16B-aligned, ~2-way banks)
constexpr int RING = 32;   // h ring depth (stale-L2-copy eviction guarantee)
constexpr int OBR  = 32;   // obuf ring depth
constexpr int SZA  = Bsz * K1;   // RH0 slot elements (36 chunks)
constexpr int SLOT = Bsz * Hsz;  // RH1 / H1h slot elements (32 chunks)
constexpr int NPH  = 256 + 3 * Tsz;  // 640 phases

// Gate permutation: tile nt (64 gate-rows) holds all 4 gates for 16 hidden units.
DI int perm_to_orig(int np) {
    int nt = np >> 6, r = np & 63, g = r >> 4, jo = r & 15;
    return g * Hsz + nt * 16 + jo;
}

// ---- MFMA fragment-packed layouts (lane-contiguous, 1KB per wave-load) ----
DI size_t wfrag(int np, int k) {   // weights: 256 row-tiles per k-chunk
    return ((size_t)((k >> 5) * 256 + (np >> 4)) * 64 + ((k >> 3) & 3) * 16 + (np & 15)) * 8 + (k & 7);
}
DI size_t afrag(int b, int k) {    // activations: 16 row-tiles per k-chunk
    return ((size_t)((k >> 5) * 16 + (b >> 4)) * 64 + ((k >> 3) & 3) * 16 + (b & 15)) * 8 + (k & 7);
}
DI size_t lfrag(int f, int k) {    // linW: 2 row-tiles per k-chunk
    return ((size_t)((k >> 5) * 2 + (f >> 4)) * 64 + ((k >> 3) & 3) * 16 + (f & 15)) * 8 + (k & 7);
}

// write-through (agent-scope) stores: land at the coherence point, no dirty L2 line
DI void store8_wt(half_t* p, half4v v) {
    unsigned long long bits;
    __builtin_memcpy(&bits, &v, 8);
    __hip_atomic_store((unsigned long long*)p, bits, __ATOMIC_RELAXED, __HIP_MEMORY_SCOPE_AGENT);
}
DI void store4_wt(half_t* p, half_t a, half_t b) {
    half_t t2[2] = {a, b};
    unsigned bits;
    __builtin_memcpy(&bits, t2, 4);
    __hip_atomic_store((unsigned*)p, bits, __ATOMIC_RELAXED, __HIP_MEMORY_SCOPE_AGENT);
}

// coherence-point 16B read via two agent-scope atomic 8B loads (round-10 fix):
// agent-scope atomic loads CANNOT be served from a stale non-coherent L1/L2 line
// — guaranteed fresh regardless of cache-eviction dynamics. Used for the one
// cross-WG datum read with (previously) a normal cached load: the obuf y-frags.
DI half8 load16_coh(const half_t* p) {
    unsigned long long lo = __hip_atomic_load((const unsigned long long*)p,
                                              __ATOMIC_RELAXED, __HIP_MEMORY_SCOPE_AGENT);
    unsigned long long hi = __hip_atomic_load((const unsigned long long*)(p + 4),
                                              __ATOMIC_RELAXED, __HIP_MEMORY_SCOPE_AGENT);
    unsigned long long arr[2] = {lo, hi};
    half8 v;
    __builtin_memcpy(&v, arr, 16);
    return v;
}

// ---------------- prep kernels ----------------

__global__ void pack_cat(half_t* __restrict__ dst, const float* __restrict__ srcA, int KA,
                         const float* __restrict__ srcB, int KB, int KP) {
    int tid = threadIdx.x;
    int np = blockIdx.y * 64 + (tid & 63);
    int k0 = (blockIdx.x * 4 + (tid >> 6)) * 8;
    if (k0 >= KP) return;
    int n = perm_to_orig(np);
    half8 v;
#pragma unroll
    for (int j = 0; j < 8; ++j) {
        int k = k0 + j;
        float f = 0.f;
        if (k < KA) f = srcA[(size_t)n * KA + k];
        else if (k < KA + KB) f = srcB[(size_t)n * KB + (k - KA)];
        v[j] = (half_t)f;
    }
    *(half8*)(dst + wfrag(np, k0)) = v;
}

// linW frag-pack + stage x(0) -> RH0 slot 0 x-cols + stage x(T-1) -> obuf slot OBR-1 (flat)
__global__ void pack_small(half_t* __restrict__ linWp, half_t* __restrict__ slot0,
                           half_t* __restrict__ obufL,
                           const float* __restrict__ linW, const float* __restrict__ inseq) {
    int idx = blockIdx.x * 256 + threadIdx.x;
    if (idx < 32 * (Hsz / 8)) {
        int f = idx & 31, k0 = (idx >> 5) * 8;
        half8 v;
#pragma unroll
        for (int j = 0; j < 8; ++j) v[j] = (half_t)linW[(size_t)f * Hsz + k0 + j];
        *(half8*)(linWp + lfrag(f, k0)) = v;
    }
    if (idx < Bsz * 4) {
        int b = idx >> 2, f0 = (idx & 3) * 8;
        half8 v, u;
#pragma unroll
        for (int j = 0; j < 8; ++j) {
            v[j] = (half_t)inseq[(size_t)b * (Tsz * Fsz) + f0 + j];
            u[j] = (half_t)inseq[(size_t)b * (Tsz * Fsz) + (Tsz - 1) * Fsz + f0 + j];
        }
        *(half8*)(slot0 + afrag(b, 1024 + f0)) = v;
        *(half8*)(obufL + (size_t)b * Fsz + f0) = u;
    }
}

// 4 permuted f32 bias vectors
__global__ void pack_bias(float* __restrict__ b4, const float* eb0, const float* eb1,
                          const float* db0, const float* db1) {
    int idx = blockIdx.x * 256 + threadIdx.x;
    if (idx >= 4 * NG) return;
    int which = idx >> 12, np = idx & (NG - 1);
    int n = perm_to_orig(np);
    const float* src = which == 0 ? eb0 : which == 1 ? eb1 : which == 2 ? db0 : db1;
    b4[idx] = src[n];
}

// ---------------- megakernel ----------------

struct MegaArgs {
    const float* in_seq;
    const half_t *W0e, *W1e, *W0d, *W1d, *linWp;
    const float *lin_b;
    const float *be1, *be2, *bd1, *bd2;
    half_t *RH0, *RH1, *H1h, *obuf;
    float* ybuf;
    unsigned* cnt;
};

DI void group_wait(unsigned* cnt, unsigned tgt, int tid) {
    if (tgt) {
        if (tid == 0) {
            // relaxed spin; NO acquire fence (agent-acquire buffer_inv would evict
            // the resident weight panels from L2 — round 3's 7GB lesson)
            while (__hip_atomic_load(cnt, __ATOMIC_RELAXED, __HIP_MEMORY_SCOPE_AGENT) < tgt)
                __builtin_amdgcn_s_sleep(1);
        }
        __syncthreads();
        // Consumer-side ordering fence (round-9 replay-race fix): block compiler
        // from hoisting A loads above the spin (IR + machine-scheduler level).
        asm volatile("" ::: "memory");
        __builtin_amdgcn_sched_barrier(0);
    }
}

// GEMM(256 x 4096 x K) + LSTM cell. c-state lives in LDS (persistent WG->CU).
// A loads are NONTEMPORAL (evict-first in L2) so streaming A cannot evict the
// resident weight panels. K1 phases: wave 3 skips zero-pad chunks (kk>=6).
// XM=1 (dec L0): wave 3's kk==5 (chunk 32 = x = y(t-1)) comes from flat obuf
// via AGENT-SCOPE ATOMIC loads (guaranteed fresh — round-10 replay-race fix:
// NT streaming removed the eviction pressure that kept normal obuf reads fresh).
template <int K, int XM>
DI void gemm_phase(const half_t* __restrict__ A0, const half_t* __restrict__ A1,
                   const half_t* __restrict__ W, const float* __restrict__ bias,
                   float (&cls)[2][64][CSTR], int ci, half_t* __restrict__ hdst,
                   const half_t* __restrict__ xobuf,
                   const float* __restrict__ xsrc, half_t* __restrict__ xdst,
                   int mt, int nt, int tid, unsigned* cnt, unsigned tgt,
                   float (&red)[4][64][RSTR]) {
    constexpr int CHW = (K / 32) / 4;  // k-chunks per wave: 9 (K1) or 16 (K2)
    int lane = tid & 63, w = tid >> 6;
    int l15 = lane & 15, l4 = lane >> 4;
    const half_t* abase;
    int cb;
    if (K == K1)     { abase = A0; cb = w * CHW; }
    else if (w < 2)  { abase = A0; cb = w * CHW; }
    else             { abase = A1; cb = (w - 2) * CHW; }
    const half_t* pa = abase + ((size_t)(cb * 16 + mt * 4) * 64 + lane) * 8;
    const half_t* pw = W + ((size_t)((w * CHW) * 256 + nt * 4) * 64 + lane) * 8;
    const bool w3k1 = (K == K1) && (w == 3);  // wave-uniform: pad-chunk skipping
    const half_t* pobuf = (XM == 1) ? (xobuf + (size_t)mt * 2048 + l15 * 32 + l4 * 8) : nullptr;

    f32x4 acc[4][4] = {};
    half8 bA[3][4], bW[3][4];

#define LDW(st, kk)                                                                  \
    {                                                                                \
        if (!(w3k1 && (kk) >= 6)) {                                                  \
            _Pragma("unroll") for (int ni = 0; ni < 4; ++ni)                         \
                bW[st][ni] = *(const half8*)(pw + (size_t)(kk) * 131072 + ni * 512); \
        }                                                                            \
    }
#define LDA(st, kk)                                                                  \
    {                                                                                \
        if (XM == 1 && w3k1 && (kk) == 5) {                                          \
            _Pragma("unroll") for (int mi = 0; mi < 4; ++mi)                         \
                bA[st][mi] = load16_coh(pobuf + mi * 512);                           \
        } else if (!(w3k1 && (kk) >= 6)) {                                           \
            _Pragma("unroll") for (int mi = 0; mi < 4; ++mi)                         \
                bA[st][mi] = __builtin_nontemporal_load(                             \
                    (const half8*)(pa + (size_t)(kk) * 8192 + mi * 512));            \
        }                                                                            \
    }

    // W prefetch before the wait: weights are constant, barrier-independent
    LDW(0, 0)
    LDW(1, 1)

    group_wait(cnt, tgt, tid);

    LDA(0, 0)
    LDA(1, 1)
#pragma unroll
    for (int kk = 0; kk < CHW; ++kk) {
        if (kk + 2 < CHW) { LDW((kk + 2) % 3, kk + 2) LDA((kk + 2) % 3, kk + 2) }
        const int st = kk % 3;
        if (!(w3k1 && kk >= 6)) {
#pragma unroll
            for (int mi = 0; mi < 4; ++mi)
#pragma unroll
                for (int ni = 0; ni < 4; ++ni)
                    acc[mi][ni] = __builtin_amdgcn_mfma_f32_16x16x32_f16(bA[st][mi], bW[st][ni], acc[mi][ni], 0, 0, 0);
        }
    }
#undef LDW
#undef LDA

    // cross-wave K reduction via LDS
#pragma unroll
    for (int mi = 0; mi < 4; ++mi)
#pragma unroll
        for (int ni = 0; ni < 4; ++ni)
#pragma unroll
            for (int r = 0; r < 4; ++r)
                red[w][mi * 16 + l4 * 4 + r][ni * 16 + l15] = acc[mi][ni][r];
    __syncthreads();

    // fused LSTM epilogue: thread -> (1 row, 4 hidden units); c-state in LDS
    int row = tid >> 2, q = tid & 3, jo0 = q * 4;
    f32x4 g0 = {}, g1 = {}, g2 = {}, g3 = {};
#pragma unroll
    for (int ww = 0; ww < 4; ++ww) {
        g0 += *(const f32x4*)&red[ww][row][jo0];
        g1 += *(const f32x4*)&red[ww][row][16 + jo0];
        g2 += *(const f32x4*)&red[ww][row][32 + jo0];
        g3 += *(const f32x4*)&red[ww][row][48 + jo0];
    }
    const float* bb = bias + nt * 64;
    g0 += *(const f32x4*)(bb + jo0);
    g1 += *(const f32x4*)(bb + 16 + jo0);
    g2 += *(const f32x4*)(bb + 32 + jo0);
    g3 += *(const f32x4*)(bb + 48 + jo0);

    int bglob = mt * 64 + row;
    int jg0 = nt * 16 + jo0;
    f32x4 cold = *(const f32x4*)&cls[ci][row][jo0];
    f32x4 cnew;
    half4v hv;
#pragma unroll
    for (int e = 0; e < 4; ++e) {
        float si = 1.f / (1.f + __expf(-g0[e]));
        float sf = 1.f / (1.f + __expf(-g1[e]));
        float tg = 1.f - 2.f / (__expf(2.f * g2[e]) + 1.f);
        float so = 1.f / (1.f + __expf(-g3[e]));
        float cn = sf * cold[e] + si * tg;
        cnew[e] = cn;
        float th = 1.f - 2.f / (__expf(2.f * cn) + 1.f);
        hv[e] = (half_t)(so * th);
    }
    *(f32x4*)&cls[ci][row][jo0] = cnew;

    store8_wt(hdst + afrag(bglob, jg0), hv);

    // stage next encoder input x (f32 -> f16, frag cols 1024..1056); nt==0 WGs only
    if (xsrc && nt == 0) {
        int f0 = q * 8;
        const float* xs = xsrc + (size_t)bglob * (Tsz * Fsz) + f0;
        half_t v[8];
#pragma unroll
        for (int j = 0; j < 8; ++j) v[j] = (half_t)xs[j];
        half4v lo = {v[0], v[1], v[2], v[3]}, hi = {v[4], v[5], v[6], v[7]};
        half_t* xp = xdst + afrag(bglob, 1024 + f0);
        store8_wt(xp, lo);
        store8_wt(xp + 4, hi);
    }
}

// OUT phase: y(t) = h1(t) @ linW^T + lin_b -> ybuf (f32, plain) + flat obuf slot (f16, WT).
// 16 worker WGs (nt<4); others just pass the barrier. h1 reads nontemporal.
DI void out_phase(const half_t* __restrict__ h1, const half_t* __restrict__ lw,
                  const float* __restrict__ lb, float* __restrict__ ybt,
                  half_t* __restrict__ ob,
                  int mt, int nt, int tid, unsigned* cnt, unsigned tgt,
                  float (&red)[4][64][RSTR]) {
    int lane = tid & 63, w = tid >> 6;
    bool worker = (nt < 4);
    int rt = mt * 4 + nt;  // 16-row batch tile index

    group_wait(cnt, tgt, tid);

    if (worker) {
        const half_t* pa = h1 + ((size_t)((w * 8) * 16 + rt) * 64 + lane) * 8;
        const half_t* pb = lw + ((size_t)(w * 8) * 2 * 64 + lane) * 8;
        f32x4 ac0 = {}, ac1 = {};
#pragma unroll
        for (int kk = 0; kk < 8; ++kk) {
            half8 a = __builtin_nontemporal_load((const half8*)(pa + (size_t)kk * 8192));
            half8 b0 = *(const half8*)(pb + kk * 1024);
            half8 b1 = *(const half8*)(pb + kk * 1024 + 512);
            ac0 = __builtin_amdgcn_mfma_f32_16x16x32_f16(a, b0, ac0, 0, 0, 0);
            ac1 = __builtin_amdgcn_mfma_f32_16x16x32_f16(a, b1, ac1, 0, 0, 0);
        }
        int l15 = lane & 15, l4 = lane >> 4;
#pragma unroll
        for (int r = 0; r < 4; ++r) {
            red[w][l4 * 4 + r][l15] = ac0[r];
            red[w][l4 * 4 + r][16 + l15] = ac1[r];
        }
    }
    __syncthreads();
    if (worker) {
        int row = tid >> 4;        // 0..15
        int f0 = (tid & 15) * 2;   // 0,2,..,30
        float v0 = red[0][row][f0] + red[1][row][f0] + red[2][row][f0] + red[3][row][f0] + lb[f0];
        float v1 = red[0][row][f0 + 1] + red[1][row][f0 + 1] + red[2][row][f0 + 1] + red[3][row][f0 + 1] + lb[f0 + 1];
        int bglob = mt * 64 + nt * 16 + row;
        float* yp = ybt + (size_t)bglob * (Tsz * Fsz);
        yp[f0] = v0;
        yp[f0 + 1] = v1;
        store4_wt(ob + (size_t)bglob * Fsz + f0, (half_t)v0, (half_t)v1);
    }
}

__launch_bounds__(256, 1) __global__ void mega_kernel(MegaArgs g) {
    __shared__ __align__(16) float red[4][64][RSTR];   // 86 KB
    __shared__ __align__(16) float cls[2][64][CSTR];   // 12 KB persistent c-state
    int bid = blockIdx.x;
    // XCD swizzle: the 4 mt-tiles sharing a weight panel land on one XCD
    int low3 = bid & 7, rest = bid >> 3;
    int mt = rest & 3, nt = ((rest >> 2) << 3) | low3;
    int tid = threadIdx.x;
    unsigned* cnt = g.cnt + mt * 64;  // one counter per row-block group (64 WGs)

    // zero-init c-state (deterministic per launch)
    for (int i = tid; i < 2 * 64 * CSTR; i += 256) ((float*)cls)[i] = 0.f;
    __syncthreads();

#pragma unroll 1
    for (int p = 0; p < NPH; ++p) {
        unsigned tgt = 64u * (unsigned)p;
        if (p < 256) {
            int t = p >> 1;
            if (!(p & 1)) {  // enc L0: K1, A=[h0(t-1)|x(t)|0] in RH0 slot t
                gemm_phase<K1, 0>(g.RH0 + (size_t)(t & (RING - 1)) * SZA, nullptr,
                                  g.W0e, g.be1, cls, 0,
                                  g.RH0 + (size_t)((t + 1) & (RING - 1)) * SZA,
                                  nullptr, nullptr, nullptr,
                                  mt, nt, tid, cnt, tgt, red);
            } else {         // enc L1: K2, A=[h0(t) | h1(t-1)]; stages x(t+1)
                int tsel = (t + 1 < Tsz) ? t + 1 : Tsz - 1;
                gemm_phase<K2, 0>(g.RH0 + (size_t)((t + 1) & (RING - 1)) * SZA,
                                  g.RH1 + (size_t)(t & (RING - 1)) * SLOT,
                                  g.W1e, g.be2, cls, 1,
                                  g.RH1 + (size_t)((t + 1) & (RING - 1)) * SLOT,
                                  nullptr,
                                  g.in_seq + (size_t)tsel * Fsz,
                                  g.RH0 + (size_t)((t + 1) & (RING - 1)) * SZA,
                                  mt, nt, tid, cnt, tgt, red);
            }
        } else {
            int qq = p - 256;
            int t = qq / 3, r = qq - t * 3;
            if (r == 0) {        // dec L0: K1 XM=1, A=h0-slot + y(t-1) from flat obuf
                gemm_phase<K1, 1>(g.RH0 + (size_t)((128 + t) & (RING - 1)) * SZA, nullptr,
                                  g.W0d, g.bd1, cls, 0,
                                  g.RH0 + (size_t)((128 + t + 1) & (RING - 1)) * SZA,
                                  g.obuf + (size_t)((t + OBR - 1) & (OBR - 1)) * (Bsz * Fsz),
                                  nullptr, nullptr,
                                  mt, nt, tid, cnt, tgt, red);
            } else if (r == 1) { // dec L1: K2, A=[h0(t) | h1(t-1)]
                gemm_phase<K2, 0>(g.RH0 + (size_t)((128 + t + 1) & (RING - 1)) * SZA,
                                  (t == 0) ? g.RH1 : g.H1h + (size_t)(t - 1) * SLOT,
                                  g.W1d, g.bd2, cls, 1,
                                  g.H1h + (size_t)t * SLOT,
                                  nullptr, nullptr, nullptr,
                                  mt, nt, tid, cnt, tgt, red);
            } else {             // OUT: y(t) -> ybuf + obuf slot (t mod OBR)
                out_phase(g.H1h + (size_t)t * SLOT, g.linWp, g.lin_b,
                          g.ybuf + (size_t)t * Fsz,
                          g.obuf + (size_t)(t & (OBR - 1)) * (Bsz * Fsz),
                          mt, nt, tid, cnt, tgt, red);
            }
        }
        // arrive: __syncthreads drains the WT stores of all waves, then one add
        __syncthreads();
        if (tid == 0)
            __hip_atomic_fetch_add(cnt, 1u, __ATOMIC_RELAXED, __HIP_MEMORY_SCOPE_AGENT);
    }
}

// ---------------- trailing copy: d_out = ybuf (kernel-boundary visibility) ----------------
__global__ void copy_out(const float* __restrict__ src, float* __restrict__ dst) {
    int i = blockIdx.x * 256 + threadIdx.x;
    ((f32x4*)dst)[i] = ((const f32x4*)src)[i];
}

// ---------------- host ----------------

extern "C" void kernel_launch(void* const* d_in, const int* in_sizes, int n_in,
                              void* d_out, int out_size, void* d_ws, size_t ws_size,
                              hipStream_t stream) {
    (void)in_sizes; (void)n_in;
    const float* in_seq = (const float*)d_in[0];
    const float* eWih0 = (const float*)d_in[1];
    const float* eWhh0 = (const float*)d_in[2];
    const float* eb0 = (const float*)d_in[3];
    const float* eWih1 = (const float*)d_in[4];
    const float* eWhh1 = (const float*)d_in[5];
    const float* eb1 = (const float*)d_in[6];
    const float* dWih0 = (const float*)d_in[7];
    const float* dWhh0 = (const float*)d_in[8];
    const float* db0 = (const float*)d_in[9];
    const float* dWih1 = (const float*)d_in[10];
    const float* dWhh1 = (const float*)d_in[11];
    const float* db1 = (const float*)d_in[12];
    const float* linW = (const float*)d_in[13];
    const float* linb = (const float*)d_in[14];
    float* out = (float*)d_out;

    char* base = (char*)d_ws;
    size_t off = 0;
    auto alloc = [&](size_t bytes) {
        char* r = base + off;
        off = (off + bytes + 255) & ~(size_t)255;
        return r;
    };
    half_t* W0e = (half_t*)alloc((size_t)NG * K1 * 2);   // 9.4 MB
    half_t* W1e = (half_t*)alloc((size_t)NG * K2 * 2);   // 16.8 MB
    half_t* W0d = (half_t*)alloc((size_t)NG * K1 * 2);
    half_t* W1d = (half_t*)alloc((size_t)NG * K2 * 2);
    half_t* linWp = (half_t*)alloc((size_t)32 * Hsz * 2);
    float* bias4 = (float*)alloc((size_t)4 * NG * 4);
    half_t* RH0 = (half_t*)alloc((size_t)RING * SZA * 2);   // 18.9 MB
    half_t* RH1 = (half_t*)alloc((size_t)RING * SLOT * 2);  // 16.8 MB
    half_t* H1h = (half_t*)alloc((size_t)Tsz * SLOT * 2);   // 67 MB
    half_t* obuf = (half_t*)alloc((size_t)OBR * Bsz * Fsz * 2);  // 512 KB
    float* ybuf = (float*)alloc((size_t)Bsz * Tsz * Fsz * 4);    // 4.2 MB
    unsigned* barCnt = (unsigned*)alloc(4 * 64 * sizeof(unsigned));

    if (off > ws_size) {  // clean failure signature: all-zero output
        hipMemsetAsync(d_out, 0, (size_t)out_size * 4, stream);
        return;
    }

    // ---- prep (re-run every call; graph-replay safe) ----
    // whole RH0 ring: zeroes h0(-1), all pad columns (1056..1152), x-cols
    hipMemsetAsync(RH0, 0, (size_t)RING * SZA * 2, stream);
    hipMemsetAsync(RH1, 0, (size_t)SLOT * 2, stream);  // h1(-1) = 0
    hipMemsetAsync(barCnt, 0, 4 * 64 * sizeof(unsigned), stream);

    pack_cat<<<dim3(K1 / 32, NG / 64), 256, 0, stream>>>(W0e, eWhh0, 1024, eWih0, 32, K1);
    pack_cat<<<dim3(K2 / 32, NG / 64), 256, 0, stream>>>(W1e, eWih1, 1024, eWhh1, 1024, K2);
    pack_cat<<<dim3(K1 / 32, NG / 64), 256, 0, stream>>>(W0d, dWhh0, 1024, dWih0, 32, K1);
    pack_cat<<<dim3(K2 / 32, NG / 64), 256, 0, stream>>>(W1d, dWih1, 1024, dWhh1, 1024, K2);
    pack_small<<<16, 256, 0, stream>>>(linWp, RH0, obuf + (size_t)(OBR - 1) * (Bsz * Fsz),
                                       linW, in_seq);
    pack_bias<<<(4 * NG + 255) / 256, 256, 0, stream>>>(bias4, eb0, eb1, db0, db1);

    MegaArgs ma;
    ma.in_seq = in_seq;
    ma.W0e = W0e; ma.W1e = W1e; ma.W0d = W0d; ma.W1d = W1d; ma.linWp = linWp;
    ma.lin_b = linb;
    ma.be1 = bias4; ma.be2 = bias4 + NG; ma.bd1 = bias4 + 2 * NG; ma.bd2 = bias4 + 3 * NG;
    ma.RH0 = RH0; ma.RH1 = RH1; ma.H1h = H1h; ma.obuf = obuf;
    ma.ybuf = ybuf;
    ma.cnt = barCnt;
    void* kargs[] = {&ma};
    hipError_t ce = hipLaunchCooperativeKernel((const void*)mega_kernel, dim3(256), dim3(256),
                                               kargs, 0, stream);
    if (ce != hipSuccess) {
        // fallback: plain launch — 256 WGs x 1/CU on a 256-CU chip is co-resident
        mega_kernel<<<dim3(256), dim3(256), 0, stream>>>(ma);
    }

    copy_out<<<(Bsz * Tsz * Fsz / 4) / 256, 256, 0, stream>>>(ybuf, out);
}

// Round 12
// 6598.822 us; speedup vs baseline: 1.5544x; 1.5544x over previous
//
#include <hip/hip_runtime.h>

typedef _Float16 half_t;
typedef _Float16 half8 __attribute__((ext_vector_type(8)));
typedef _Float16 half4v __attribute__((ext_vector_type(4)));
typedef float f32x4 __attribute__((ext_vector_type(4)));

#define DI __device__ __forceinline__

constexpr int Bsz = 256;   // batch
constexpr int Tsz = 128;   // seq len
constexpr int Fsz = 32;    // feature
constexpr int Hsz = 1024;  // hidden
constexpr int NG  = 4096;  // 4*H gate rows
constexpr int K1  = 1152;  // [h(1024) | x(32) | pad(96)=0]
constexpr int K2  = 2048;  // [h0 | h1]
constexpr int RSTR = 84;   // LDS reduce stride
constexpr int CSTR = 24;   // LDS c-state stride (96B rows)
constexpr int RING = 32;   // ring depth (stale-L2-line eviction guarantee)
constexpr int SZA = Bsz * K1;
constexpr int SZB = Bsz * K2;

// Gate permutation: tile nt (64 gate-rows) holds all 4 gates for 16 hidden units.
DI int perm_to_orig(int np) {
    int nt = np >> 6, r = np & 63, g = r >> 4, jo = r & 15;
    return g * Hsz + nt * 16 + jo;
}

// ---- MFMA fragment-packed layouts (lane-contiguous, 1KB per wave-load) ----
DI size_t wfrag(int np, int k) {
    return ((size_t)((k >> 5) * 256 + (np >> 4)) * 64 + ((k >> 3) & 3) * 16 + (np & 15)) * 8 + (k & 7);
}
DI size_t afrag(int b, int k) {
    return ((size_t)((k >> 5) * 16 + (b >> 4)) * 64 + ((k >> 3) & 3) * 16 + (b & 15)) * 8 + (k & 7);
}

// write-through (agent-scope) stores: land at the coherence point, no dirty L2 line
DI void store8_wt(half_t* p, half4v v) {
    unsigned long long bits;
    __builtin_memcpy(&bits, &v, 8);
    __hip_atomic_store((unsigned long long*)p, bits, __ATOMIC_RELAXED, __HIP_MEMORY_SCOPE_AGENT);
}

// ---------------- prep kernels ----------------

__global__ void pack_cat(half_t* __restrict__ dst, const float* __restrict__ srcA, int KA,
                         const float* __restrict__ srcB, int KB, int KP) {
    int tid = threadIdx.x;
    int np = blockIdx.y * 64 + (tid & 63);
    int k0 = (blockIdx.x * 4 + (tid >> 6)) * 8;
    if (k0 >= KP) return;
    int n = perm_to_orig(np);
    half8 v;
#pragma unroll
    for (int j = 0; j < 8; ++j) {
        int k = k0 + j;
        float f = 0.f;
        if (k < KA) f = srcA[(size_t)n * KA + k];
        else if (k < KA + KB) f = srcB[(size_t)n * KB + (k - KA)];
        v[j] = (half_t)f;
    }
    *(half8*)(dst + wfrag(np, k0)) = v;
}

// Fill dst cols [1024,2048) with Wfold[n][h] = sum_f Wih0[n][f]*linW[f][h]
__global__ void pack_fold(half_t* __restrict__ dst, const float* __restrict__ Wih0,
                          const float* __restrict__ linW) {
    __shared__ float lw[32][128];
    __shared__ float wi[16][32];
    int nb = blockIdx.x * 16;
    int jb = blockIdx.y * 128;
    int t = threadIdx.x;
    for (int i = t; i < 32 * 128; i += 256) { int f = i >> 7, j = i & 127; lw[f][j] = linW[f * Hsz + jb + j]; }
    for (int i = t; i < 16 * 32; i += 256) { int r = i >> 5, f = i & 31; wi[r][f] = Wih0[perm_to_orig(nb + r) * 32 + f]; }
    __syncthreads();
    int r = t >> 4, j0 = (t & 15) * 8;
    half8 v;
#pragma unroll
    for (int jj = 0; jj < 8; ++jj) {
        float s = 0.f;
#pragma unroll
        for (int f = 0; f < 32; ++f) s += wi[r][f] * lw[f][j0 + jj];
        v[jj] = (half_t)s;
    }
    *(half8*)(dst + wfrag(nb + r, 1024 + jb + j0)) = v;
}

// 5 permuted f32 bias vectors; slot 3 = dec_b0 + Wih0@lin_b (folded)
__global__ void pack_bias(float* __restrict__ b5, const float* eb0, const float* eb1,
                          const float* db0, const float* db1, const float* dWih0,
                          const float* linb) {
    int idx = blockIdx.x * 256 + threadIdx.x;
    if (idx >= 5 * NG) return;
    int which = idx >> 12, np = idx & (NG - 1);
    int n = perm_to_orig(np);
    float v;
    if (which == 0) v = eb0[n];
    else if (which == 1) v = eb1[n];
    else if (which == 2) v = db0[n];
    else if (which == 3) {
        v = db0[n];
        for (int f = 0; f < 32; ++f) v += dWih0[n * 32 + f] * linb[f];
    } else v = db1[n];
    b5[idx] = v;
}

// lin_W f32->f16 (row-major) + stage x(0) into ringA slot 0 frag x-cols
__global__ void pack_small(half_t* __restrict__ Wlin, half_t* __restrict__ slot0,
                           const float* __restrict__ linW, const float* __restrict__ inseq) {
    int idx = blockIdx.x * 256 + threadIdx.x;
    if (idx < 32 * Hsz) Wlin[idx] = (half_t)linW[idx];
    if (idx < Bsz * 4) {
        int b = idx >> 2, fg = idx & 3;
        half8 v;
#pragma unroll
        for (int j = 0; j < 8; ++j) v[j] = (half_t)inseq[(size_t)b * (Tsz * Fsz) + fg * 8 + j];
        *(half8*)(slot0 + afrag(b, 1024 + fg * 8)) = v;
    }
}

// ---------------- megakernel: all 512 phases, r4 skeleton ----------------

struct MegaArgs {
    const float* in_seq;
    const half_t *Wenc1, *Wenc2, *Wdec1a, *Wdec1b, *Wdec2;
    const float *be1, *be2, *bd1a, *bd1b, *bd2;
    half_t *ringA, *ringB, *ringD, *H1hist;
    unsigned* cnt;
};

struct PhaseDesc {
    const half_t* A; const half_t* W; const float* bias; int ci;
    half_t* h0; int cb0; half_t* h1; int cb1; half_t* h2; int cb2;
    const float* xs; half_t* xd; int K;
};

DI PhaseDesc make_desc(int p, const MegaArgs& g) {
    PhaseDesc d = {};
    if (p < 256) {
        int t = p >> 1;
        if ((p & 1) == 0) {  // enc L0 (K1): A = ringA[t] = [h0(t-1)|x(t)|0]
            d.A = g.ringA + (size_t)(t & (RING - 1)) * SZA;
            d.W = g.Wenc1; d.bias = g.be1; d.ci = 0;
            d.h0 = g.ringB + (size_t)(t & (RING - 1)) * SZB; d.cb0 = 0;
            d.h1 = g.ringA + (size_t)((t + 1) & (RING - 1)) * SZA; d.cb1 = 0;
            d.K = K1;
        } else {             // enc L1 (K2): A = ringB[t] = [h0(t)|h1(t-1)]; stages x(t+1)
            int tsel = (t + 1 < Tsz) ? t + 1 : Tsz - 1;
            d.A = g.ringB + (size_t)(t & (RING - 1)) * SZB;
            d.W = g.Wenc2; d.bias = g.be2; d.ci = 1;
            d.h0 = g.ringB + (size_t)((t + 1) & (RING - 1)) * SZB; d.cb0 = 1024;
            d.xs = g.in_seq + (size_t)tsel * Fsz;
            d.xd = g.ringA + (size_t)((t + 1) & (RING - 1)) * SZA;
            d.K = K2;
        }
    } else if (p == 256) {   // dec t=0 L0 (K1): A = ringA[128%RING] = [h0_enc|x_last]
        d.A = g.ringA + (size_t)(128 & (RING - 1)) * SZA;
        d.W = g.Wdec1a; d.bias = g.bd1a; d.ci = 0;
        d.h0 = g.ringB + (size_t)(128 & (RING - 1)) * SZB; d.cb0 = 0;
        d.h1 = g.ringD + (size_t)(1 & (RING - 1)) * SZB; d.cb1 = 0;
        d.K = K1;
    } else if (p == 257) {   // dec t=0 L1 (K2): A = ringB[128%RING] = [h0d(0)|h1_enc]
        d.A = g.ringB + (size_t)(128 & (RING - 1)) * SZB;
        d.W = g.Wdec2; d.bias = g.bd2; d.ci = 1;
        d.h0 = g.ringB + (size_t)(129 & (RING - 1)) * SZB; d.cb0 = 1024;
        d.h1 = g.ringD + (size_t)(1 & (RING - 1)) * SZB; d.cb1 = 1024;
        d.h2 = g.H1hist; d.cb2 = 0;
        d.K = K2;
    } else {
        int t = (p - 256) >> 1;  // decoder step (t >= 1)
        int u = 128 + t;
        if ((p & 1) == 0) {      // dec L0 folded (K2): A = ringD[t] = [h0d(t-1)|h1d(t-1)]
            d.A = g.ringD + (size_t)(t & (RING - 1)) * SZB;
            d.W = g.Wdec1b; d.bias = g.bd1b; d.ci = 0;
            d.h0 = g.ringB + (size_t)(u & (RING - 1)) * SZB; d.cb0 = 0;
            d.h1 = g.ringD + (size_t)((t + 1) & (RING - 1)) * SZB; d.cb1 = 0;
            d.K = K2;
        } else {                 // dec L1 (K2): A = ringB[u] = [h0d(t)|h1d(t-1)]
            d.A = g.ringB + (size_t)(u & (RING - 1)) * SZB;
            d.W = g.Wdec2; d.bias = g.bd2; d.ci = 1;
            d.h0 = g.ringB + (size_t)((u + 1) & (RING - 1)) * SZB; d.cb0 = 1024;
            d.h1 = g.ringD + (size_t)((t + 1) & (RING - 1)) * SZB; d.cb1 = 1024;
            d.h2 = g.H1hist + (size_t)t * (Bsz * Hsz); d.cb2 = 0;
            d.K = K2;
        }
    }
    return d;
}

DI void group_wait(unsigned* cnt, unsigned tgt, int tid) {
    if (tgt) {
        if (tid == 0) {
            // relaxed spin; NO acquire fence (agent-acquire buffer_inv would evict
            // the resident weight panels from L2 — round 3's 7GB lesson)
            while (__hip_atomic_load(cnt, __ATOMIC_RELAXED, __HIP_MEMORY_SCOPE_AGENT) < tgt)
                __builtin_amdgcn_s_sleep(1);
        }
        __syncthreads();
        // Consumer-side ordering fence (round-9-proven replay-race fix): stops the
        // compiler/scheduler hoisting A loads above the spin. Zero runtime cost.
        asm volatile("" ::: "memory");
        __builtin_amdgcn_sched_barrier(0);
    }
}

// GEMM(256 x 4096 x K) + fused LSTM cell. Waves split K; LDS reduce; c in LDS.
// K1: wave 3 skips zero-pad chunks (local kk>=6 == global chunks 33..35).
template <int K>
DI void run_phase(const PhaseDesc& d, float (&cls)[2][64][CSTR],
                  int mt, int nt, int tid, unsigned* cnt, unsigned tgt,
                  float (&red)[4][64][RSTR]) {
    constexpr int CHW = (K / 32) / 4;  // 9 (K1) or 16 (K2)
    int lane = tid & 63, w = tid >> 6;
    int l15 = lane & 15, l4 = lane >> 4;
    const half_t* pa = d.A + ((size_t)((w * CHW) * 16 + mt * 4) * 64 + lane) * 8;
    const half_t* pw = d.W + ((size_t)((w * CHW) * 256 + nt * 4) * 64 + lane) * 8;
    const bool w3k1 = (K == K1) && (w == 3);  // wave-uniform pad skip

    f32x4 acc[4][4] = {};
    half8 bA[3][4], bW[3][4];

#define LDW(st, kk)                                                                \
    {                                                                              \
        if (!(w3k1 && (kk) >= 6)) {                                                \
            _Pragma("unroll") for (int ni = 0; ni < 4; ++ni)                       \
                bW[st][ni] = *(const half8*)(pw + (size_t)(kk) * 131072 + ni * 512); \
        }                                                                          \
    }
#define LDA(st, kk)                                                                \
    {                                                                              \
        if (!(w3k1 && (kk) >= 6)) {                                                \
            _Pragma("unroll") for (int mi = 0; mi < 4; ++mi)                       \
                bA[st][mi] = *(const half8*)(pa + (size_t)(kk) * 8192 + mi * 512); \
        }                                                                          \
    }

    // W prefetch before the wait: weights are constant, barrier-independent
    LDW(0, 0)
    LDW(1, 1)

    group_wait(cnt, tgt, tid);

    LDA(0, 0)
    LDA(1, 1)
#pragma unroll
    for (int kk = 0; kk < CHW; ++kk) {
        if (kk + 2 < CHW) { LDW((kk + 2) % 3, kk + 2) LDA((kk + 2) % 3, kk + 2) }
        const int st = kk % 3;
        if (!(w3k1 && kk >= 6)) {
#pragma unroll
            for (int mi = 0; mi < 4; ++mi)
#pragma unroll
                for (int ni = 0; ni < 4; ++ni)
                    acc[mi][ni] = __builtin_amdgcn_mfma_f32_16x16x32_f16(bA[st][mi], bW[st][ni], acc[mi][ni], 0, 0, 0);
        }
    }
#undef LDW
#undef LDA

    // cross-wave K reduction via LDS
#pragma unroll
    for (int mi = 0; mi < 4; ++mi)
#pragma unroll
        for (int ni = 0; ni < 4; ++ni)
#pragma unroll
            for (int r = 0; r < 4; ++r)
                red[w][mi * 16 + l4 * 4 + r][ni * 16 + l15] = acc[mi][ni][r];
    __syncthreads();

    // fused LSTM epilogue: thread -> (1 row, 4 hidden units); c-state in LDS
    int row = tid >> 2, q = tid & 3, jo0 = q * 4;
    f32x4 g0 = {}, g1 = {}, g2 = {}, g3 = {};
#pragma unroll
    for (int ww = 0; ww < 4; ++ww) {
        g0 += *(const f32x4*)&red[ww][row][jo0];
        g1 += *(const f32x4*)&red[ww][row][16 + jo0];
        g2 += *(const f32x4*)&red[ww][row][32 + jo0];
        g3 += *(const f32x4*)&red[ww][row][48 + jo0];
    }
    const float* bb = d.bias + nt * 64;
    g0 += *(const f32x4*)(bb + jo0);
    g1 += *(const f32x4*)(bb + 16 + jo0);
    g2 += *(const f32x4*)(bb + 32 + jo0);
    g3 += *(const f32x4*)(bb + 48 + jo0);

    int bglob = mt * 64 + row;
    int jg0 = nt * 16 + jo0;
    f32x4 cold = *(const f32x4*)&cls[d.ci][row][jo0];
    f32x4 cnew;
    half4v hv;
#pragma unroll
    for (int e = 0; e < 4; ++e) {
        float si = 1.f / (1.f + __expf(-g0[e]));
        float sf = 1.f / (1.f + __expf(-g1[e]));
        float tg = 1.f - 2.f / (__expf(2.f * g2[e]) + 1.f);
        float so = 1.f / (1.f + __expf(-g3[e]));
        float cn = sf * cold[e] + si * tg;
        cnew[e] = cn;
        float th = 1.f - 2.f / (__expf(2.f * cn) + 1.f);
        hv[e] = (half_t)(so * th);
    }
    *(f32x4*)&cls[d.ci][row][jo0] = cnew;

    {
        int col = d.cb0 + jg0;
        store8_wt(d.h0 + afrag(bglob, col), hv);
    }
    if (d.h1) {
        int col = d.cb1 + jg0;
        store8_wt(d.h1 + afrag(bglob, col), hv);
    }
    if (d.h2) {
        int col = d.cb2 + jg0;
        store8_wt(d.h2 + afrag(bglob, col), hv);
    }

    // stage next encoder input x (f32 -> f16, frag cols 1024..1056); nt==0 WGs only
    if (d.xs && nt == 0) {
        int f0 = q * 8;
        const float* xs = d.xs + (size_t)bglob * (Tsz * Fsz) + f0;
        half_t v[8];
#pragma unroll
        for (int j = 0; j < 8; ++j) v[j] = (half_t)xs[j];
        half4v lo = {v[0], v[1], v[2], v[3]}, hi = {v[4], v[5], v[6], v[7]};
        half_t* xp = d.xd + afrag(bglob, 1024 + f0);
        store8_wt(xp, lo);
        store8_wt(xp + 4, hi);
    }
}

__launch_bounds__(256, 1) __global__ void mega_kernel(MegaArgs g) {
    __shared__ __align__(16) float red[4][64][RSTR];  // 86 KB
    __shared__ __align__(16) float cls[2][64][CSTR];  // 12 KB persistent c-state
    int bid = blockIdx.x;
    // XCD swizzle: the 4 mt-tiles sharing a weight panel land on one XCD
    int low3 = bid & 7, rest = bid >> 3;
    int mt = rest & 3, nt = ((rest >> 2) << 3) | low3;
    int tid = threadIdx.x;
    unsigned* cnt = g.cnt + mt * 64;  // one counter per row-block group (64 WGs)

    // zero-init c-state (deterministic per launch)
    for (int i = tid; i < 2 * 64 * CSTR; i += 256) ((float*)cls)[i] = 0.f;
    __syncthreads();

#pragma unroll 1
    for (int p = 0; p < 512; ++p) {
        PhaseDesc d = make_desc(p, g);
        if (d.K == K1) run_phase<K1>(d, cls, mt, nt, tid, cnt, (unsigned)(64 * p), red);
        else           run_phase<K2>(d, cls, mt, nt, tid, cnt, (unsigned)(64 * p), red);
        // arrive: __syncthreads drains the WT h-stores of all waves, then one add
        __syncthreads();
        if (tid == 0)
            __hip_atomic_fetch_add(cnt, 1u, __ATOMIC_RELAXED, __HIP_MEMORY_SCOPE_AGENT);
    }
}

// ---------------- final projection: out[b][t][f] = H1hist[t](frag) . lin_W[f][:] + lin_b
__launch_bounds__(256, 1) __global__
void lin_out(const half_t* __restrict__ H1, const half_t* __restrict__ Wl,
             const float* __restrict__ lb, float* __restrict__ out) {
    int w = threadIdx.x >> 6, lane = threadIdx.x & 63;
    int l15 = lane & 15, l4 = lane >> 4;
    int rowt = blockIdx.x * 4 + w;
    int t = rowt >> 4, mi = rowt & 15;
    const half_t* pa = H1 + (size_t)t * (Bsz * Hsz);
    const half_t* pb0 = Wl + (size_t)l15 * Hsz + l4 * 8;
    const half_t* pb1 = Wl + (size_t)(16 + l15) * Hsz + l4 * 8;
    f32x4 ac0 = {}, ac1 = {};
#pragma unroll 4
    for (int kc = 0; kc < 32; ++kc) {
        half8 a = *(const half8*)(pa + ((size_t)(kc * 16 + mi) * 64 + lane) * 8);
        half8 b0 = *(const half8*)(pb0 + kc * 32);
        half8 b1 = *(const half8*)(pb1 + kc * 32);
        ac0 = __builtin_amdgcn_mfma_f32_16x16x32_f16(a, b0, ac0, 0, 0, 0);
        ac1 = __builtin_amdgcn_mfma_f32_16x16x32_f16(a, b1, ac1, 0, 0, 0);
    }
#pragma unroll
    for (int r = 0; r < 4; ++r) {
        int row = rowt * 16 + l4 * 4 + r;  // flat = t*256 + b
        int b = row & 255;
        size_t o = (size_t)b * (Tsz * Fsz) + t * Fsz;
        out[o + l15] = ac0[r] + lb[l15];
        out[o + 16 + l15] = ac1[r] + lb[16 + l15];
    }
}

// ---------------- host ----------------

extern "C" void kernel_launch(void* const* d_in, const int* in_sizes, int n_in,
                              void* d_out, int out_size, void* d_ws, size_t ws_size,
                              hipStream_t stream) {
    (void)in_sizes; (void)n_in;
    const float* in_seq = (const float*)d_in[0];
    const float* eWih0 = (const float*)d_in[1];
    const float* eWhh0 = (const float*)d_in[2];
    const float* eb0 = (const float*)d_in[3];
    const float* eWih1 = (const float*)d_in[4];
    const float* eWhh1 = (const float*)d_in[5];
    const float* eb1 = (const float*)d_in[6];
    const float* dWih0 = (const float*)d_in[7];
    const float* dWhh0 = (const float*)d_in[8];
    const float* db0 = (const float*)d_in[9];
    const float* dWih1 = (const float*)d_in[10];
    const float* dWhh1 = (const float*)d_in[11];
    const float* db1 = (const float*)d_in[12];
    const float* linW = (const float*)d_in[13];
    const float* linb = (const float*)d_in[14];
    float* out = (float*)d_out;

    char* base = (char*)d_ws;
    size_t off = 0;
    auto alloc = [&](size_t bytes) {
        char* r = base + off;
        off = (off + bytes + 255) & ~(size_t)255;
        return r;
    };
    half_t* Wenc1 = (half_t*)alloc((size_t)NG * K1 * 2);
    half_t* Wenc2 = (half_t*)alloc((size_t)NG * K2 * 2);
    half_t* Wdec1a = (half_t*)alloc((size_t)NG * K1 * 2);
    half_t* Wdec1b = (half_t*)alloc((size_t)NG * K2 * 2);
    half_t* Wdec2 = (half_t*)alloc((size_t)NG * K2 * 2);
    half_t* Wlin = (half_t*)alloc((size_t)32 * Hsz * 2);
    float* bias5 = (float*)alloc((size_t)5 * NG * 4);
    half_t* ringA = (half_t*)alloc((size_t)RING * SZA * 2);  // 18.9 MB
    half_t* ringB = (half_t*)alloc((size_t)RING * SZB * 2);  // 33.6 MB
    half_t* ringD = (half_t*)alloc((size_t)RING * SZB * 2);  // 33.6 MB
    half_t* H1hist = (half_t*)alloc((size_t)Tsz * Bsz * Hsz * 2);  // 67 MB
    unsigned* barCnt = (unsigned*)alloc(4 * 64 * sizeof(unsigned));

    if (off > ws_size) {  // clean failure signature: all-zero output
        hipMemsetAsync(d_out, 0, (size_t)out_size * 4, stream);
        return;
    }

    float* be1 = bias5;
    float* be2 = bias5 + NG;
    float* bd1a = bias5 + 2 * NG;
    float* bd1b = bias5 + 3 * NG;
    float* bd2 = bias5 + 4 * NG;

    // ---- prep (re-run every call; graph-replay safe) ----
    hipMemsetAsync(ringA, 0, (size_t)RING * SZA * 2, stream);  // h0(-1), x, pads = 0
    hipMemsetAsync(ringB, 0, (size_t)SZB * 2, stream);         // slot 0: h1(-1) = 0
    hipMemsetAsync(barCnt, 0, 4 * 64 * sizeof(unsigned), stream);

    pack_cat<<<dim3(K1 / 32, NG / 64), 256, 0, stream>>>(Wenc1, eWhh0, 1024, eWih0, 32, K1);
    pack_cat<<<dim3(K2 / 32, NG / 64), 256, 0, stream>>>(Wenc2, eWih1, 1024, eWhh1, 1024, K2);
    pack_cat<<<dim3(K1 / 32, NG / 64), 256, 0, stream>>>(Wdec1a, dWhh0, 1024, dWih0, 32, K1);
    pack_cat<<<dim3(K2 / 32, NG / 64), 256, 0, stream>>>(Wdec1b, dWhh0, 1024, nullptr, 0, K2);
    pack_fold<<<dim3(NG / 16, 1024 / 128), 256, 0, stream>>>(Wdec1b, dWih0, linW);
    pack_cat<<<dim3(K2 / 32, NG / 64), 256, 0, stream>>>(Wdec2, dWih1, 1024, dWhh1, 1024, K2);
    pack_bias<<<(5 * NG + 255) / 256, 256, 0, stream>>>(bias5, eb0, eb1, db0, db1, dWih0, linb);
    pack_small<<<128, 256, 0, stream>>>(Wlin, ringA, linW, in_seq);

    MegaArgs ma;
    ma.in_seq = in_seq;
    ma.Wenc1 = Wenc1; ma.Wenc2 = Wenc2;
    ma.Wdec1a = Wdec1a; ma.Wdec1b = Wdec1b; ma.Wdec2 = Wdec2;
    ma.be1 = be1; ma.be2 = be2; ma.bd1a = bd1a; ma.bd1b = bd1b; ma.bd2 = bd2;
    ma.ringA = ringA; ma.ringB = ringB; ma.ringD = ringD;
    ma.H1hist = H1hist;
    ma.cnt = barCnt;
    void* kargs[] = {&ma};
    hipError_t ce = hipLaunchCooperativeKernel((const void*)mega_kernel, dim3(256), dim3(256),
                                               kargs, 0, stream);
    if (ce != hipSuccess) {
        // fallback: plain launch — 256 WGs x 1/CU on a 256-CU chip is co-resident
        mega_kernel<<<dim3(256), dim3(256), 0, stream>>>(ma);
    }

    lin_out<<<512, 256, 0, stream>>>(H1hist, Wlin, linb, out);
}